// Round 10
// baseline (988.712 us; speedup 1.0000x reference)
//
#include <hip/hip_runtime.h>

#define T_STEPS 10000
#define BATCH   512

__device__ __forceinline__ float fexp2(float x) {
#if __has_builtin(__builtin_amdgcn_exp2f)
  return __builtin_amdgcn_exp2f(x);
#else
  return exp2f(x);
#endif
}

__device__ __forceinline__ float frcp(float x) {
#if __has_builtin(__builtin_amdgcn_rcpf)
  return __builtin_amdgcn_rcpf(x);
#else
  return 1.0f / x;
#endif
}

// Quad-local permute: lane j of each quad receives from lane sel_j.
template <int CTRL>
__device__ __forceinline__ float qperm(float v) {
  int i = __builtin_bit_cast(int, v);
#if __has_builtin(__builtin_amdgcn_mov_dpp)
  int r = __builtin_amdgcn_mov_dpp(i, CTRL, 0xF, 0xF, true);
#else
  int r = __builtin_amdgcn_ds_swizzle(i, 0x8000 | CTRL);
#endif
  return __builtin_bit_cast(float, r);
}

// Roles in a quad (b = tid>>2, role = tid&3):
//  r0: f_W/c_W | r1: f_N/c_N | r2: f_R/c_R | r3: h/0
// Scheme (validated R4-R9, absmax pinned at exact kernel's 0.0039):
//  * main sigmoid frozen per step, midpoint-extrapolated coupling (EXT=3.5)
//  * c-sigmoid affine, now 16-step refresh (install at +2); P folded in
//  * RK4 step in closed affine form (basis-extracted coefficients)
//  * 3-stage software pipeline of the G package (R8); burst loads (R9)
// New in R10 (issue-slot diet):
//  * uniform-base (SALU-advanced) + per-lane-constant-index addressing for
//    ALL loads/stores -> zero VALU address math
//  * single merged coupling dpp: pub = role{0,3}?mf:mc, one qperm<0x1E>,
//    per-lane W2 weight; Yc tree = 4 fma
//  * role3's second store retargeted to its own h slot with value q0
//    (writes h twice; order-independent) -> no divergent store, no ws base
__global__ __launch_bounds__(64, 1)
void sleep_rk4_kernel(const float* __restrict__ noise,
                      const float* __restrict__ pgRRe,
                      const float* __restrict__ pgRWe,
                      const float* __restrict__ pgWNi,
                      const float* __restrict__ pgWRi,
                      const float* __restrict__ pgNRi,
                      const float* __restrict__ pgNWi,
                      float* __restrict__ out)
{
  const int tid  = (int)(blockIdx.x * 64u + threadIdx.x);
  const int b    = tid >> 2;
  const int role = tid & 3;

  const float g_RRe = *pgRRe, g_RWe = *pgRWe, g_WNi = *pgWNi;
  const float g_WRi = *pgWRi, g_NRi = *pgNRi, g_NWi = *pgNWi;

  const float L2E = 1.4426950408889634f;
  const float LN2 = 0.6931471805599453f;

  float W1, W2, W3, NSC, BB, qa, qb, pa, pb, cs, ia, ib;
  float f0, c0;
  int v0i, v1i;
  bool dostore1, role03;

  if (role == 0) {              // f_W / c_W
    const float SC = 2.0f * L2E / 0.5f;
    W1 = SC * g_NWi; W2 = SC * g_RWe; W3 = 0.0f; NSC = SC; BB = SC * 0.4f;
    qa = -1.0f / 1.5e6f; qb = 6.5f / 1.5e6f; pa = 0.0f; pb = -6.5f / 1.5e6f;
    cs = 2.0f * L2E / 5.0f; ia = -1.0f / 2.5e4f; ib = 1.0f / 2.5e4f;
    f0 = 6.0f; c0 = 0.9f; v0i = 0; v1i = 3; dostore1 = true;  role03 = true;
  } else if (role == 1) {       // f_N / c_N
    const float SC = 2.0f * L2E / 0.175f;
    W1 = SC * g_WNi; W2 = SC * 1.5f; W3 = 0.0f; NSC = SC; BB = 0.0f;
    qa = -1.0f / 6.0e5f; qb = 5.0f / 6.0e5f; pa = 0.0f; pb = -5.0f / 6.0e5f;
    cs = 2.0f * L2E / 4.0f; ia = -1.0f / 1.0e4f; ib = 1.0f / 1.0e4f;
    f0 = 1.0e-3f; c0 = 1.0e-3f; v0i = 1; v1i = 4; dostore1 = true;  role03 = false;
  } else if (role == 2) {       // f_R / c_R
    const float SC = 2.0f * L2E / 0.13f;
    W1 = SC * g_WRi; W2 = SC * g_NRi; W3 = SC * g_RRe; NSC = SC; BB = SC * 0.9f;
    qa = -1.0f / 6.0e4f; qb = 5.0f / 6.0e4f; pa = 0.0f; pb = -5.0f / 6.0e4f;
    cs = 2.0f * L2E / 2.0f; ia = -1.0f / 1.0e4f; ib = 1.0f / 1.0e4f;
    f0 = 1.0e-3f; c0 = 1.0e-3f; v0i = 2; v1i = 5; dostore1 = true;  role03 = false;
  } else {                      // h
    W1 = 0.0f; W2 = -5.0f * L2E; W3 = 0.0f; NSC = 0.0f; BB = 10.0f * L2E;
    qa = -1.0f / 3.06e7f; qb = 0.0f;
    pa = (1.0f / 3.06e7f - 1.0f / 3.483e7f);
    pb = 1.0f / 3.483e7f;
    cs = 0.0f; ia = 0.0f; ib = 0.0f;
    f0 = 0.5f; c0 = 0.0f; v0i = 6; v1i = 6; dostore1 = false; role03 = true;
  }

  const float AQAh = 0.5f * qa, AQA1 = qa;
  const float AIAh = 0.5f * ia, AIA1 = ia;
  const float IAC  = ia * cs;
  const float TIA  = 2.0f * ia;
  const float R6   = 0.16666666666666666f;

  // ---- init: closed-form step coefficients via basis runs ----
  float vF[4], vG[4];
  auto frun = [&](float f0b, float Gb, float* v) -> float {
    const float Chb = fmaf(0.5f, Gb, f0b), C1b = f0b + Gb;
    float s0 = f0b, acc = -3.0f * f0b;
    s0 = fmaf(AQAh, s0, Chb); v[0] = s0; acc = fmaf(2.0f, s0, acc);
    s0 = fmaf(AQAh, s0, Chb); v[1] = s0; acc = fmaf(4.0f, s0, acc);
    s0 = fmaf(AQA1, s0, C1b); v[2] = s0; acc = fmaf(2.0f, s0, acc);
    s0 = fmaf(AQA1, s0, C1b); v[3] = s0; acc = fmaf(1.0f, s0, acc);
    float q = acc * R6; q = fmaf(fmaf(q, -6.0f, acc), R6, q); return q;
  };
  const float KF = frun(1.0f, 0.0f, vF);
  const float KG = frun(0.0f, 1.0f, vG);

  auto crun = [&](const float* v, float c0b, float e1u, float vd1) -> float {
    const float E1h = IAC * e1u, E11 = 2.0f * IAC * e1u;
    const float Dh = c0b + 0.5f * vd1, D1 = c0b + vd1;
    float s1 = c0b, acc = -3.0f * c0b;
    s1 = fmaf(AIAh, s1, fmaf(E1h, v[0], Dh)); acc = fmaf(2.0f, s1, acc);
    s1 = fmaf(AIAh, s1, fmaf(E1h, v[1], Dh)); acc = fmaf(4.0f, s1, acc);
    s1 = fmaf(AIA1, s1, fmaf(E11, v[2], D1)); acc = fmaf(2.0f, s1, acc);
    s1 = fmaf(AIA1, s1, fmaf(E11, v[3], D1)); acc = fmaf(1.0f, s1, acc);
    float q = acc * R6; q = fmaf(fmaf(q, -6.0f, acc), R6, q); return q;
  };
  float z4[4] = {0.0f, 0.0f, 0.0f, 0.0f};
  const float KC  = crun(z4, 1.0f, 0.0f, 0.0f);
  const float LAf = crun(vF, 0.0f, 1.0f, 0.0f);
  const float LBf = crun(vG, 0.0f, 1.0f, 0.0f);
  const float KW  = crun(z4, 0.0f, 0.0f, 1.0f);

  // ---- c-sigmoid + P refresh (16-step cadence; compute/install split) ----
  float LAe, LBe, VDK, Pc, tLAe, tLBe, tVDK, tP;
  auto crefresh_compute = [&](float fcur) {
    const float zb = cs * fcur;
    const float ez = fexp2(zb);
    const float sc_ = frcp(1.0f + ez);
    const float t2 = fmaf(sc_, sc_, -sc_);
    const float e1 = LN2 * t2;
    const float vC = fmaf(-e1, zb, sc_);
    const float VD1 = fmaf(TIA, vC, ib);
    tLAe = LAf * e1; tLBe = LBf * e1; tVDK = KW * VD1;
    tP = fmaf(pa, fcur, pb);
  };
  crefresh_compute(f0);
  LAe = tLAe; LBe = tLBe; VDK = tVDK; Pc = tP;

  // ---- Yc tree (merged publish-select; 2 dpp + 1 cndmask + 4 fma) ----
  auto YcOf = [&](float no_step, float mcv, float mfv) -> float {
    const float pub = role03 ? mfv : mcv;
    const float xA  = qperm<0x01>(mcv);
    const float xB  = qperm<0x1E>(pub);
    return fmaf(W1, xA, fmaf(W2, xB, fmaf(W3, mcv, fmaf(NSC, no_step, BB))));
  };

  float dF = 0.0f, dC = 0.0f;

  // uniform bases (SALU-advanced), per-lane constant indices
  const int off0 = v0i * BATCH + b;
  const int off1 = v1i * BATCH + b;      // role3: == off0 (h slot)
  float* obase = out;

  float nbA[16], nbB[16];
  {
    const float* __restrict__ lp = noise;
#pragma unroll
    for (int j = 0; j < 16; ++j) nbA[j] = lp[b + j * BATCH];
  }

  // ---- pipeline prefill (frozen state, dx=0) ----
  float G_cur = fmaf(Pc, frcp(1.0f + fexp2(YcOf(nbA[0], c0, f0))), qb); // G(0)
  float e_pip = fexp2(YcOf(nbA[1], c0, f0));                            // e(1)
  float Yc_pip = YcOf(nbA[2], c0, f0);                                  // Yc(2)

#define BLOCK(nbC, nbN, tl)                                                   \
  do {                                                                        \
    const float* __restrict__ lp = noise + (size_t)(tl) * BATCH;              \
    _Pragma("unroll")                                                         \
    for (int j = 0; j < 16; ++j) nbN[j] = lp[b + j * BATCH];                  \
    _Pragma("unroll")                                                         \
    for (int j = 0; j < 16; ++j) {                                            \
      if (j == 0) crefresh_compute(f0);                                       \
      if (j == 2) { LAe = tLAe; LBe = tLBe; VDK = tVDK; Pc = tP; }            \
      const float no3 = (j < 13) ? nbC[j + 3] : nbN[j - 13];                  \
      const float mc  = fmaf(3.5f, dC, c0);                                   \
      const float mf  = fmaf(3.5f, dF, f0);                                   \
      const float Ycn = YcOf(no3, mc, mf);                                    \
      const float e_new = fexp2(Yc_pip);                                      \
      const float rb = frcp(1.0f + e_pip);                                    \
      const float G_new = fmaf(Pc, rb, qb);                                   \
      const float q0 = fmaf(KF, f0, KG * G_cur);                              \
      const float q1 = fmaf(KC, c0, fmaf(LAe, f0, fmaf(LBe, G_cur, VDK)));    \
      dF = q0 - f0; dC = q1 - c0;                                             \
      f0 = q0; c0 = q1;                                                       \
      G_cur = G_new; e_pip = e_new; Yc_pip = Ycn;                             \
      const float st1 = dostore1 ? q1 : q0;                                   \
      obase[off1] = st1;                                                      \
      obase[off0] = q0;                                                       \
      obase += 7 * BATCH;                                                     \
    }                                                                         \
  } while (0)

  // 312 double-blocks cover steps 0..9983; final block: steps 9984..9999
  for (int t = 0; t + 32 <= T_STEPS; t += 32) {
    const int tl2 = (t + 32 <= T_STEPS - 16) ? (t + 32) : (T_STEPS - 16);
    BLOCK(nbA, nbB, t + 16);
    BLOCK(nbB, nbA, tl2);
  }
  BLOCK(nbA, nbB, T_STEPS - 16);   // final 16 steps; reload clamp (harmless)
#undef BLOCK
}

extern "C" void kernel_launch(void* const* d_in, const int* in_sizes, int n_in,
                              void* d_out, int out_size, void* d_ws, size_t ws_size,
                              hipStream_t stream) {
  const float* noise = (const float*)d_in[0];
  const float* gRRe  = (const float*)d_in[1];
  const float* gRWe  = (const float*)d_in[2];
  const float* gWNi  = (const float*)d_in[3];
  const float* gWRi  = (const float*)d_in[4];
  const float* gNRi  = (const float*)d_in[5];
  const float* gNWi  = (const float*)d_in[6];
  float* out = (float*)d_out;

  sleep_rk4_kernel<<<dim3((BATCH * 4) / 64), dim3(64), 0, stream>>>(
      noise, gRRe, gRWe, gWNi, gWRi, gNRi, gNWi, out);
}

// Round 11
// 618.180 us; speedup vs baseline: 1.5994x; 1.5994x over previous
//
#include <hip/hip_runtime.h>

#define T_STEPS 10000
#define BATCH   512

__device__ __forceinline__ float fexp2(float x) {
#if __has_builtin(__builtin_amdgcn_exp2f)
  return __builtin_amdgcn_exp2f(x);
#else
  return exp2f(x);
#endif
}

__device__ __forceinline__ float frcp(float x) {
#if __has_builtin(__builtin_amdgcn_rcpf)
  return __builtin_amdgcn_rcpf(x);
#else
  return 1.0f / x;
#endif
}

// Pin: force value to materialize in a VGPR here (blocks load-sinking; the
// s_waitcnt for the producing load lands at this point, not at each use).
#define PIN(x) asm volatile("" : "+v"(x))

// Quad-local permute: lane j of each quad receives from lane sel_j.
template <int CTRL>
__device__ __forceinline__ float qperm(float v) {
  int i = __builtin_bit_cast(int, v);
#if __has_builtin(__builtin_amdgcn_mov_dpp)
  int r = __builtin_amdgcn_mov_dpp(i, CTRL, 0xF, 0xF, true);
#else
  int r = __builtin_amdgcn_ds_swizzle(i, 0x8000 | CTRL);
#endif
  return __builtin_bit_cast(float, r);
}

// Roles in a quad (b = tid>>2, role = tid&3):
//  r0: f_W/c_W | r1: f_N/c_N | r2: f_R/c_R | r3: h/0
// Scheme (validated R4-R9, absmax pinned at exact kernel's 0.0039):
//  * main sigmoid frozen per step, midpoint-extrapolated coupling (EXT=3.5)
//  * c-sigmoid affine, 8-step refresh (staged install at +2)
//  * RK4 step in closed affine form (basis-extracted coefficients)
//  * 3-stage software pipeline of the G package (R8)
// New in R11: TRIPLE-buffered noise with PIN barriers. Block k issues the
// 16 loads for block k+2, then pins block k's buffer (loaded 2 blocks ago)
// and the 3 head elements of block k+1's buffer -> single vmcnt(16)-class
// wait per block; loads can no longer be sunk into the iteration body
// (R10's regression mechanism, visible as VGPR 44->36).
__global__ __launch_bounds__(64, 1)
void sleep_rk4_kernel(const float* __restrict__ noise,
                      const float* __restrict__ pgRRe,
                      const float* __restrict__ pgRWe,
                      const float* __restrict__ pgWNi,
                      const float* __restrict__ pgWRi,
                      const float* __restrict__ pgNRi,
                      const float* __restrict__ pgNWi,
                      float* __restrict__ out,
                      float* __restrict__ ws)
{
  const int tid  = (int)(blockIdx.x * 64u + threadIdx.x);
  const int b    = tid >> 2;
  const int role = tid & 3;

  const float g_RRe = *pgRRe, g_RWe = *pgRWe, g_WNi = *pgWNi;
  const float g_WRi = *pgWRi, g_NRi = *pgNRi, g_NWi = *pgNWi;

  const float L2E = 1.4426950408889634f;
  const float LN2 = 0.6931471805599453f;

  float W1, W2A, W2B, W3, NSC, BB, qa, qb, pa, pb, cs, ia, ib;
  float f0, c0;
  int v0i, v1i;
  bool dostore1;

  if (role == 0) {              // f_W / c_W
    const float SC = 2.0f * L2E / 0.5f;
    W1 = SC * g_NWi; W2A = SC * g_RWe; W2B = 0.0f; W3 = 0.0f; NSC = SC; BB = SC * 0.4f;
    qa = -1.0f / 1.5e6f; qb = 6.5f / 1.5e6f; pa = 0.0f; pb = -6.5f / 1.5e6f;
    cs = 2.0f * L2E / 5.0f; ia = -1.0f / 2.5e4f; ib = 1.0f / 2.5e4f;
    f0 = 6.0f; c0 = 0.9f; v0i = 0; v1i = 3; dostore1 = true;
  } else if (role == 1) {       // f_N / c_N
    const float SC = 2.0f * L2E / 0.175f;
    W1 = SC * g_WNi; W2A = 0.0f; W2B = SC * 1.5f; W3 = 0.0f; NSC = SC; BB = 0.0f;
    qa = -1.0f / 6.0e5f; qb = 5.0f / 6.0e5f; pa = 0.0f; pb = -5.0f / 6.0e5f;
    cs = 2.0f * L2E / 4.0f; ia = -1.0f / 1.0e4f; ib = 1.0f / 1.0e4f;
    f0 = 1.0e-3f; c0 = 1.0e-3f; v0i = 1; v1i = 4; dostore1 = true;
  } else if (role == 2) {       // f_R / c_R
    const float SC = 2.0f * L2E / 0.13f;
    W1 = SC * g_WRi; W2A = SC * g_NRi; W2B = 0.0f; W3 = SC * g_RRe; NSC = SC; BB = SC * 0.9f;
    qa = -1.0f / 6.0e4f; qb = 5.0f / 6.0e4f; pa = 0.0f; pb = -5.0f / 6.0e4f;
    cs = 2.0f * L2E / 2.0f; ia = -1.0f / 1.0e4f; ib = 1.0f / 1.0e4f;
    f0 = 1.0e-3f; c0 = 1.0e-3f; v0i = 2; v1i = 5; dostore1 = true;
  } else {                      // h
    W1 = 0.0f; W2A = 0.0f; W2B = -5.0f * L2E; W3 = 0.0f; NSC = 0.0f; BB = 10.0f * L2E;
    qa = -1.0f / 3.06e7f; qb = 0.0f;
    pa = (1.0f / 3.06e7f - 1.0f / 3.483e7f);
    pb = 1.0f / 3.483e7f;
    cs = 0.0f; ia = 0.0f; ib = 0.0f;
    f0 = 0.5f; c0 = 0.0f; v0i = 6; v1i = 0; dostore1 = false;
  }

  const float AQAh = 0.5f * qa, AQA1 = qa;
  const float AIAh = 0.5f * ia, AIA1 = ia;
  const float IAC  = ia * cs;
  const float TIA  = 2.0f * ia;
  const float R6   = 0.16666666666666666f;

  // ---- init: closed-form step coefficients via basis runs ----
  float vF[4], vG[4];
  auto frun = [&](float f0b, float Gb, float* v) -> float {
    const float Chb = fmaf(0.5f, Gb, f0b), C1b = f0b + Gb;
    float s0 = f0b, acc = -3.0f * f0b;
    s0 = fmaf(AQAh, s0, Chb); v[0] = s0; acc = fmaf(2.0f, s0, acc);
    s0 = fmaf(AQAh, s0, Chb); v[1] = s0; acc = fmaf(4.0f, s0, acc);
    s0 = fmaf(AQA1, s0, C1b); v[2] = s0; acc = fmaf(2.0f, s0, acc);
    s0 = fmaf(AQA1, s0, C1b); v[3] = s0; acc = fmaf(1.0f, s0, acc);
    float q = acc * R6; q = fmaf(fmaf(q, -6.0f, acc), R6, q); return q;
  };
  const float KF = frun(1.0f, 0.0f, vF);
  const float KG = frun(0.0f, 1.0f, vG);

  auto crun = [&](const float* v, float c0b, float e1u, float vd1) -> float {
    const float E1h = IAC * e1u, E11 = 2.0f * IAC * e1u;
    const float Dh = c0b + 0.5f * vd1, D1 = c0b + vd1;
    float s1 = c0b, acc = -3.0f * c0b;
    s1 = fmaf(AIAh, s1, fmaf(E1h, v[0], Dh)); acc = fmaf(2.0f, s1, acc);
    s1 = fmaf(AIAh, s1, fmaf(E1h, v[1], Dh)); acc = fmaf(4.0f, s1, acc);
    s1 = fmaf(AIA1, s1, fmaf(E11, v[2], D1)); acc = fmaf(2.0f, s1, acc);
    s1 = fmaf(AIA1, s1, fmaf(E11, v[3], D1)); acc = fmaf(1.0f, s1, acc);
    float q = acc * R6; q = fmaf(fmaf(q, -6.0f, acc), R6, q); return q;
  };
  float z4[4] = {0.0f, 0.0f, 0.0f, 0.0f};
  const float KC  = crun(z4, 1.0f, 0.0f, 0.0f);
  const float LAf = crun(vF, 0.0f, 1.0f, 0.0f);
  const float LBf = crun(vG, 0.0f, 1.0f, 0.0f);
  const float KW  = crun(z4, 0.0f, 0.0f, 1.0f);

  // ---- c-sigmoid refresh (compute/install split, off-chain) ----
  float LAe, LBe, VDK, tLAe, tLBe, tVDK;
  auto crefresh_compute = [&](float fcur) {
    const float zb = cs * fcur;
    const float ez = fexp2(zb);
    const float sc_ = frcp(1.0f + ez);
    const float t2 = fmaf(sc_, sc_, -sc_);
    const float e1 = LN2 * t2;
    const float vC = fmaf(-e1, zb, sc_);
    const float VD1 = fmaf(TIA, vC, ib);
    tLAe = LAf * e1; tLBe = LBf * e1; tVDK = KW * VD1;
  };
  crefresh_compute(f0);
  LAe = tLAe; LBe = tLBe; VDK = tVDK;

  // ---- Yc tree for a given noise and coupling snapshot ----
  auto YcOf = [&](float no_step, float mcv, float mfv) -> float {
    const float NBv = fmaf(NSC, no_step, BB);
    const float xA  = qperm<0x01>(mcv);
    const float xBa = qperm<0x1E>(mcv);
    const float xBb = qperm<0x1E>(mfv);
    float Yc = fmaf(W3, mcv, NBv);
    Yc = fmaf(W2A, xBa, Yc);
    Yc = fmaf(W1, xA, Yc);
    Yc = fmaf(W2B, xBb, Yc);
    return Yc;
  };

  float dF = 0.0f, dC = 0.0f;

  const float* nptr = noise + b;
  float* ob0 = out + v0i * BATCH + b;
  float* ob1 = dostore1 ? (out + v1i * BATCH + b) : (ws + b);
  const int adv1 = dostore1 ? 7 * BATCH : 0;

  float nb0[16], nb1[16], nb2[16];
#pragma unroll
  for (int j = 0; j < 16; ++j) nb0[j] = nptr[(size_t)j * BATCH];
#pragma unroll
  for (int j = 0; j < 16; ++j) nb1[j] = nptr[(size_t)(16 + j) * BATCH];

  // ---- pipeline prefill (frozen state, dx=0) ----
  const float Pw = fmaf(pa, f0, pb);
  float G_cur = fmaf(Pw, frcp(1.0f + fexp2(YcOf(nb0[0], c0, f0))), qb); // G(0)
  float e_pip = fexp2(YcOf(nb0[1], c0, f0));                            // e(1)
  float Yc_pip = YcOf(nb0[2], c0, f0);                                  // Yc(2)

  int base = 0;

  // One 16-step block: consume nbC (steps base..base+15) and nbN[0..2];
  // issue 16 loads for block base+32 into nbL; pin nbC + nbN head.
#define TBLOCK(nbC, nbN, nbL)                                                 \
  do {                                                                        \
    int tl = base + 32; if (tl > T_STEPS - 16) tl = T_STEPS - 16;             \
    const float* __restrict__ lp = nptr + (size_t)tl * BATCH;                 \
    _Pragma("unroll")                                                         \
    for (int j = 0; j < 16; ++j) nbL[j] = lp[(size_t)j * BATCH];              \
    _Pragma("unroll")                                                         \
    for (int j = 0; j < 16; ++j) PIN(nbC[j]);                                 \
    PIN(nbN[0]); PIN(nbN[1]); PIN(nbN[2]);                                    \
    _Pragma("unroll")                                                         \
    for (int j = 0; j < 16; ++j) {                                            \
      if ((j & 7) == 0) crefresh_compute(f0);                                 \
      if ((j & 7) == 2) { LAe = tLAe; LBe = tLBe; VDK = tVDK; }               \
      const float no3 = (j < 13) ? nbC[j + 3] : nbN[j - 13];                  \
      const float mc  = fmaf(3.5f, dC, c0);                                   \
      const float mf  = fmaf(3.5f, dF, f0);                                   \
      const float Ycn = YcOf(no3, mc, mf);                                    \
      const float e_new = fexp2(Yc_pip);                                      \
      const float rb = frcp(1.0f + e_pip);                                    \
      const float P  = fmaf(pa, f0, pb);                                      \
      const float G_new = fmaf(P, rb, qb);                                    \
      const float q0 = fmaf(KF, f0, KG * G_cur);                              \
      const float q1 = fmaf(KC, c0, fmaf(LAe, f0, fmaf(LBe, G_cur, VDK)));    \
      dF = q0 - f0; dC = q1 - c0;                                             \
      f0 = q0; c0 = q1;                                                       \
      G_cur = G_new; e_pip = e_new; Yc_pip = Ycn;                             \
      ob0[0] = q0;                                                            \
      ob1[0] = q1;                                                            \
      ob0 += 7 * BATCH;                                                       \
      ob1 += adv1;                                                            \
    }                                                                         \
    base += 16;                                                               \
  } while (0)

  // 625 blocks total = 208 triples + 1 (tail G-pipeline reads of steps
  // >= T_STEPS use clamped reloads -> finite garbage, never consumed).
  for (int kk = 0; kk < 208; ++kk) {
    TBLOCK(nb0, nb1, nb2);
    TBLOCK(nb1, nb2, nb0);
    TBLOCK(nb2, nb0, nb1);
  }
  TBLOCK(nb0, nb1, nb2);
#undef TBLOCK
}

extern "C" void kernel_launch(void* const* d_in, const int* in_sizes, int n_in,
                              void* d_out, int out_size, void* d_ws, size_t ws_size,
                              hipStream_t stream) {
  const float* noise = (const float*)d_in[0];
  const float* gRRe  = (const float*)d_in[1];
  const float* gRWe  = (const float*)d_in[2];
  const float* gWNi  = (const float*)d_in[3];
  const float* gWRi  = (const float*)d_in[4];
  const float* gNRi  = (const float*)d_in[5];
  const float* gNWi  = (const float*)d_in[6];
  float* out = (float*)d_out;
  float* ws  = (float*)d_ws;

  sleep_rk4_kernel<<<dim3((BATCH * 4) / 64), dim3(64), 0, stream>>>(
      noise, gRRe, gRWe, gWNi, gWRi, gNRi, gNWi, out, ws);
}

// Round 12
// 523.701 us; speedup vs baseline: 1.8879x; 1.1804x over previous
//
#include <hip/hip_runtime.h>

#define T_STEPS 10000
#define BATCH   512

__device__ __forceinline__ float fexp2(float x) {
#if __has_builtin(__builtin_amdgcn_exp2f)
  return __builtin_amdgcn_exp2f(x);
#else
  return exp2f(x);
#endif
}

__device__ __forceinline__ float frcp(float x) {
#if __has_builtin(__builtin_amdgcn_rcpf)
  return __builtin_amdgcn_rcpf(x);
#else
  return 1.0f / x;
#endif
}

// Pin: force value into a VGPR here (blocks load-sinking; R11-validated).
#define PIN(x) asm volatile("" : "+v"(x))

// Quad-local permute: lane j of each quad receives from lane sel_j.
template <int CTRL>
__device__ __forceinline__ float qperm(float v) {
  int i = __builtin_bit_cast(int, v);
#if __has_builtin(__builtin_amdgcn_mov_dpp)
  int r = __builtin_amdgcn_mov_dpp(i, CTRL, 0xF, 0xF, true);
#else
  int r = __builtin_amdgcn_ds_swizzle(i, 0x8000 | CTRL);
#endif
  return __builtin_bit_cast(float, r);
}

// Roles in a quad (b = tid>>2, role = tid&3):
//  r0: f_W/c_W | r1: f_N/c_N | r2: f_R/c_R | r3: h/0
// Scheme (validated R4-R11, absmax pinned at exact kernel's 0.0039):
//  * main sigmoid frozen per step, extrapolated coupling (base state s,
//    one-step slope d): m(target) = x + EXT*d
//  * c-sigmoid affine, 16-step refresh, P folded (R10-validated numerics)
//  * RK4 step in closed affine form (basis-extracted coefficients)
// New in R12: 4-step GROUPS. The coupling tree is LINEAR, so per group:
//    YB = tree(state), dY = tree(delta)  (2 trees, 4 dpp, merged-pub)
//    y_k = NSC*no_k + YB + EXT_k*dY, EXT_k = 4.5,5.5,6.5,7.5 (next group)
//  -> exp/add/rcp run as 4 INDEPENDENT chains (in-order issue never starves)
//  -> step-map is the only serial recursion (4 fma/group).
__global__ __launch_bounds__(64, 1)
void sleep_rk4_kernel(const float* __restrict__ noise,
                      const float* __restrict__ pgRRe,
                      const float* __restrict__ pgRWe,
                      const float* __restrict__ pgWNi,
                      const float* __restrict__ pgWRi,
                      const float* __restrict__ pgNRi,
                      const float* __restrict__ pgNWi,
                      float* __restrict__ out)
{
  const int tid  = (int)(blockIdx.x * 64u + threadIdx.x);
  const int b    = tid >> 2;
  const int role = tid & 3;

  const float g_RRe = *pgRRe, g_RWe = *pgRWe, g_WNi = *pgWNi;
  const float g_WRi = *pgWRi, g_NRi = *pgNRi, g_NWi = *pgNWi;

  const float L2E = 1.4426950408889634f;
  const float LN2 = 0.6931471805599453f;

  float W1, W2, W3, NSC, BB, qa, qb, pa, pb, cs, ia, ib;
  float f0, c0;
  int v0i, v1i;
  bool dostore1, role03;

  if (role == 0) {              // f_W / c_W
    const float SC = 2.0f * L2E / 0.5f;
    W1 = SC * g_NWi; W2 = SC * g_RWe; W3 = 0.0f; NSC = SC; BB = SC * 0.4f;
    qa = -1.0f / 1.5e6f; qb = 6.5f / 1.5e6f; pa = 0.0f; pb = -6.5f / 1.5e6f;
    cs = 2.0f * L2E / 5.0f; ia = -1.0f / 2.5e4f; ib = 1.0f / 2.5e4f;
    f0 = 6.0f; c0 = 0.9f; v0i = 0; v1i = 3; dostore1 = true;  role03 = true;
  } else if (role == 1) {       // f_N / c_N
    const float SC = 2.0f * L2E / 0.175f;
    W1 = SC * g_WNi; W2 = SC * 1.5f; W3 = 0.0f; NSC = SC; BB = 0.0f;
    qa = -1.0f / 6.0e5f; qb = 5.0f / 6.0e5f; pa = 0.0f; pb = -5.0f / 6.0e5f;
    cs = 2.0f * L2E / 4.0f; ia = -1.0f / 1.0e4f; ib = 1.0f / 1.0e4f;
    f0 = 1.0e-3f; c0 = 1.0e-3f; v0i = 1; v1i = 4; dostore1 = true;  role03 = false;
  } else if (role == 2) {       // f_R / c_R
    const float SC = 2.0f * L2E / 0.13f;
    W1 = SC * g_WRi; W2 = SC * g_NRi; W3 = SC * g_RRe; NSC = SC; BB = SC * 0.9f;
    qa = -1.0f / 6.0e4f; qb = 5.0f / 6.0e4f; pa = 0.0f; pb = -5.0f / 6.0e4f;
    cs = 2.0f * L2E / 2.0f; ia = -1.0f / 1.0e4f; ib = 1.0f / 1.0e4f;
    f0 = 1.0e-3f; c0 = 1.0e-3f; v0i = 2; v1i = 5; dostore1 = true;  role03 = false;
  } else {                      // h
    W1 = 0.0f; W2 = -5.0f * L2E; W3 = 0.0f; NSC = 0.0f; BB = 10.0f * L2E;
    qa = -1.0f / 3.06e7f; qb = 0.0f;
    pa = (1.0f / 3.06e7f - 1.0f / 3.483e7f);
    pb = 1.0f / 3.483e7f;
    cs = 0.0f; ia = 0.0f; ib = 0.0f;
    f0 = 0.5f; c0 = 0.0f; v0i = 6; v1i = 6; dostore1 = false; role03 = true;
  }

  const float AQAh = 0.5f * qa, AQA1 = qa;
  const float AIAh = 0.5f * ia, AIA1 = ia;
  const float IAC  = ia * cs;
  const float TIA  = 2.0f * ia;
  const float R6   = 0.16666666666666666f;

  // ---- init: closed-form step coefficients via basis runs ----
  float vF[4], vG[4];
  auto frun = [&](float f0b, float Gb, float* v) -> float {
    const float Chb = fmaf(0.5f, Gb, f0b), C1b = f0b + Gb;
    float s0 = f0b, acc = -3.0f * f0b;
    s0 = fmaf(AQAh, s0, Chb); v[0] = s0; acc = fmaf(2.0f, s0, acc);
    s0 = fmaf(AQAh, s0, Chb); v[1] = s0; acc = fmaf(4.0f, s0, acc);
    s0 = fmaf(AQA1, s0, C1b); v[2] = s0; acc = fmaf(2.0f, s0, acc);
    s0 = fmaf(AQA1, s0, C1b); v[3] = s0; acc = fmaf(1.0f, s0, acc);
    float q = acc * R6; q = fmaf(fmaf(q, -6.0f, acc), R6, q); return q;
  };
  const float KF = frun(1.0f, 0.0f, vF);
  const float KG = frun(0.0f, 1.0f, vG);

  auto crun = [&](const float* v, float c0b, float e1u, float vd1) -> float {
    const float E1h = IAC * e1u, E11 = 2.0f * IAC * e1u;
    const float Dh = c0b + 0.5f * vd1, D1 = c0b + vd1;
    float s1 = c0b, acc = -3.0f * c0b;
    s1 = fmaf(AIAh, s1, fmaf(E1h, v[0], Dh)); acc = fmaf(2.0f, s1, acc);
    s1 = fmaf(AIAh, s1, fmaf(E1h, v[1], Dh)); acc = fmaf(4.0f, s1, acc);
    s1 = fmaf(AIA1, s1, fmaf(E11, v[2], D1)); acc = fmaf(2.0f, s1, acc);
    s1 = fmaf(AIA1, s1, fmaf(E11, v[3], D1)); acc = fmaf(1.0f, s1, acc);
    float q = acc * R6; q = fmaf(fmaf(q, -6.0f, acc), R6, q); return q;
  };
  float z4[4] = {0.0f, 0.0f, 0.0f, 0.0f};
  const float KC  = crun(z4, 1.0f, 0.0f, 0.0f);
  const float LAf = crun(vF, 0.0f, 1.0f, 0.0f);
  const float LBf = crun(vG, 0.0f, 1.0f, 0.0f);
  const float KW  = crun(z4, 0.0f, 0.0f, 1.0f);

  // ---- c-sigmoid + P refresh (16-step cadence; compute/install split) ----
  float LAe, LBe, VDK, Pc, tLAe, tLBe, tVDK, tP;
  auto crefresh_compute = [&](float fcur) {
    const float zb = cs * fcur;
    const float ez = fexp2(zb);
    const float sc_ = frcp(1.0f + ez);
    const float t2 = fmaf(sc_, sc_, -sc_);
    const float e1 = LN2 * t2;
    const float vC = fmaf(-e1, zb, sc_);
    const float VD1 = fmaf(TIA, vC, ib);
    tLAe = LAf * e1; tLBe = LBf * e1; tVDK = KW * VD1;
    tP = fmaf(pa, fcur, pb);
  };
  crefresh_compute(f0);
  LAe = tLAe; LBe = tLBe; VDK = tVDK; Pc = tP;

  float dF = 0.0f, dC = 0.0f;
  float Gq0, Gq1, Gq2, Gq3;

  // uniform store base + per-lane constant offsets (saddr form)
  const int off0 = v0i * BATCH + b;
  const int off1 = v1i * BATCH + b;      // role3: == off0
  float* obase = out;

  float nb0[16], nb1[16], nb2[16];
#pragma unroll
  for (int j = 0; j < 16; ++j) nb0[j] = noise[b + j * BATCH];
#pragma unroll
  for (int j = 0; j < 16; ++j) nb1[j] = noise[b + (16 + j) * BATCH];

  // ---- prefill: Gq for steps 0..3 (frozen state, zero slope) ----
  {
    const float pubS = role03 ? f0 : c0;
    const float xAs = qperm<0x01>(c0);
    const float xBs = qperm<0x1E>(pubS);
    const float YB = fmaf(W1, xAs, fmaf(W2, xBs, fmaf(W3, c0, BB)));
    Gq0 = fmaf(Pc, frcp(1.0f + fexp2(fmaf(NSC, nb0[0], YB))), qb);
    Gq1 = fmaf(Pc, frcp(1.0f + fexp2(fmaf(NSC, nb0[1], YB))), qb);
    Gq2 = fmaf(Pc, frcp(1.0f + fexp2(fmaf(NSC, nb0[2], YB))), qb);
    Gq3 = fmaf(Pc, frcp(1.0f + fexp2(fmaf(NSC, nb0[3], YB))), qb);
  }

  // One 4-step group: consumes Gq0..3, computes next group's G from the
  // two linear trees, runs 4 closed-form step-maps, updates slope.
  auto GROUP = [&](float n0, float n1, float n2, float n3) {
    // independent head (fills the wait on f0/c0 from previous group)
    const float t0 = KG * Gq0, t1 = KG * Gq1, t2 = KG * Gq2, t3 = KG * Gq3;
    // trees (linear): YB on state, dY on slope; merged-pub dpp (R10-valid)
    const float pubS = role03 ? f0 : c0;
    const float pubD = role03 ? dF : dC;
    const float xAs = qperm<0x01>(c0);
    const float xBs = qperm<0x1E>(pubS);
    const float xAd = qperm<0x01>(dC);
    const float xBd = qperm<0x1E>(pubD);
    // step-map recursion interleaved with the (independent) tree fmas
    const float f1 = fmaf(KF, f0, t0);
    float YB = fmaf(W3, c0, BB);
    float dY = W3 * dC;
    const float c1 = fmaf(KC, c0, fmaf(LAe, f0, fmaf(LBe, Gq0, VDK)));
    YB = fmaf(W2, xBs, YB);
    dY = fmaf(W2, xBd, dY);
    const float f2 = fmaf(KF, f1, t1);
    YB = fmaf(W1, xAs, YB);
    dY = fmaf(W1, xAd, dY);
    const float c2 = fmaf(KC, c1, fmaf(LAe, f1, fmaf(LBe, Gq1, VDK)));
    // y batch for next group's steps (EXT = 4.5..7.5), 4 independent chains
    const float y0 = fmaf(NSC, n0, fmaf(4.5f, dY, YB));
    const float y1 = fmaf(NSC, n1, fmaf(5.5f, dY, YB));
    const float f3 = fmaf(KF, f2, t2);
    const float y2 = fmaf(NSC, n2, fmaf(6.5f, dY, YB));
    const float y3 = fmaf(NSC, n3, fmaf(7.5f, dY, YB));
    const float c3 = fmaf(KC, c2, fmaf(LAe, f2, fmaf(LBe, Gq2, VDK)));
    const float e0 = fexp2(y0);
    const float e1_ = fexp2(y1);
    const float f4 = fmaf(KF, f3, t3);
    const float e2 = fexp2(y2);
    const float e3 = fexp2(y3);
    const float c4 = fmaf(KC, c3, fmaf(LAe, f3, fmaf(LBe, Gq3, VDK)));
    const float r0 = frcp(1.0f + e0);
    const float r1 = frcp(1.0f + e1_);
    const float r2 = frcp(1.0f + e2);
    const float r3 = frcp(1.0f + e3);
    // stores (uniform base advance; value-select for role3)
    obase[off0] = f1; obase[off1] = dostore1 ? c1 : f1; obase += 7 * BATCH;
    obase[off0] = f2; obase[off1] = dostore1 ? c2 : f2; obase += 7 * BATCH;
    obase[off0] = f3; obase[off1] = dostore1 ? c3 : f3; obase += 7 * BATCH;
    obase[off0] = f4; obase[off1] = dostore1 ? c4 : f4; obase += 7 * BATCH;
    // next-group G (consumed one group later -> full slack for exp/rcp)
    Gq0 = fmaf(Pc, r0, qb);
    Gq1 = fmaf(Pc, r1, qb);
    Gq2 = fmaf(Pc, r2, qb);
    Gq3 = fmaf(Pc, r3, qb);
    // boundary slope + state install
    dF = f4 - f3; dC = c4 - c3;
    f0 = f4; c0 = c4;
  };

  int base = 0;

  // 16-step block: issue loads for base+32, pin consumed buffers, 4 groups.
#define TBLOCK(nbC, nbN, nbL)                                                 \
  do {                                                                        \
    int tl = base + 32; if (tl > T_STEPS - 16) tl = T_STEPS - 16;             \
    const float* __restrict__ lp = noise + (size_t)tl * BATCH;                \
    _Pragma("unroll")                                                         \
    for (int j = 0; j < 16; ++j) nbL[j] = lp[b + j * BATCH];                  \
    _Pragma("unroll")                                                         \
    for (int j = 0; j < 16; ++j) PIN(nbC[j]);                                 \
    PIN(nbN[0]); PIN(nbN[1]); PIN(nbN[2]); PIN(nbN[3]);                       \
    crefresh_compute(f0);                                                     \
    GROUP(nbC[4], nbC[5], nbC[6], nbC[7]);                                    \
    LAe = tLAe; LBe = tLBe; VDK = tVDK; Pc = tP;                              \
    GROUP(nbC[8], nbC[9], nbC[10], nbC[11]);                                  \
    GROUP(nbC[12], nbC[13], nbC[14], nbC[15]);                                \
    GROUP(nbN[0], nbN[1], nbN[2], nbN[3]);                                    \
    base += 16;                                                               \
  } while (0)

  for (int kk = 0; kk < 208; ++kk) {
    TBLOCK(nb0, nb1, nb2);
    TBLOCK(nb1, nb2, nb0);
    TBLOCK(nb2, nb0, nb1);
  }
  TBLOCK(nb0, nb1, nb2);   // steps 9984..9999 (tail G reads clamped, unused)
#undef TBLOCK
}

extern "C" void kernel_launch(void* const* d_in, const int* in_sizes, int n_in,
                              void* d_out, int out_size, void* d_ws, size_t ws_size,
                              hipStream_t stream) {
  const float* noise = (const float*)d_in[0];
  const float* gRRe  = (const float*)d_in[1];
  const float* gRWe  = (const float*)d_in[2];
  const float* gWNi  = (const float*)d_in[3];
  const float* gWRi  = (const float*)d_in[4];
  const float* gNRi  = (const float*)d_in[5];
  const float* gNWi  = (const float*)d_in[6];
  float* out = (float*)d_out;

  sleep_rk4_kernel<<<dim3((BATCH * 4) / 64), dim3(64), 0, stream>>>(
      noise, gRRe, gRWe, gWNi, gWRi, gNRi, gNWi, out);
}